// Round 1
// baseline (44.937 us; speedup 1.0000x reference)
//
#include <hip/hip_runtime.h>

// Volume rendering composite forward (per-ray alpha compositing).
// One 64-lane wave per ray. Within a ray: chunked 64-wide shfl inclusive scan
// of sd = sigma*delta with a running carry gives the exclusive prefix;
// T = exp(-excl); a = 1 - exp(-sd); w = (T >= thr) ? a*T : 0.
// Per-ray sums (count/opacity/depth/rgb) accumulate in registers, butterfly
// reduced at the end. All w[] elements are written every call (d_out is
// poisoned once and never re-poisoned).

__global__ __launch_bounds__(256) void vr_fwd_kernel(
    const float* __restrict__ sigmas,
    const float* __restrict__ rgbs,
    const float* __restrict__ deltas,
    const float* __restrict__ ts,
    const int*   __restrict__ rays_a,
    const float* __restrict__ thr_p,
    float* __restrict__ out,   // counts | opacity | depth | rgb | w
    int n_rays)
{
    const int wid  = (int)((blockIdx.x * (unsigned)blockDim.x + threadIdx.x) >> 6);
    const int lane = (int)(threadIdx.x & 63u);
    if (wid >= n_rays) return;

    const int   start = rays_a[wid * 3 + 1];
    const int   count = rays_a[wid * 3 + 2];
    const float thr   = thr_p[0];

    float* __restrict__ out_counts  = out;
    float* __restrict__ out_opacity = out + n_rays;
    float* __restrict__ out_depth   = out + 2 * n_rays;
    float* __restrict__ out_rgb     = out + 3 * n_rays;
    float* __restrict__ out_w       = out + 6 * n_rays;

    float carry = 0.0f;
    float acc_n = 0.0f, acc_op = 0.0f, acc_d = 0.0f;
    float acc_r = 0.0f, acc_g = 0.0f, acc_b = 0.0f;

    for (int base = 0; base < count; base += 64) {
        const int  i     = base + lane;
        const bool valid = (i < count);
        const int  gi    = start + i;

        float sd = 0.0f;
        if (valid) sd = sigmas[gi] * deltas[gi];

        // inclusive scan across 64 lanes
        float scan = sd;
        #pragma unroll
        for (int off = 1; off < 64; off <<= 1) {
            float up = __shfl_up(scan, off, 64);
            if (lane >= off) scan += up;
        }
        const float total = __shfl(scan, 63, 64);
        const float excl  = carry + (scan - sd);
        carry += total;

        if (valid) {
            const float T     = __expf(-excl);
            const float a     = 1.0f - __expf(-sd);
            const bool  alive = (T >= thr);
            const float w     = alive ? a * T : 0.0f;
            out_w[gi] = w;
            if (alive) {
                acc_n  += 1.0f;
                acc_op += w;
                acc_d  += w * ts[gi];
                acc_r  += w * rgbs[gi * 3 + 0];
                acc_g  += w * rgbs[gi * 3 + 1];
                acc_b  += w * rgbs[gi * 3 + 2];
            }
        }
    }

    // butterfly reduce the 6 accumulators across the wave
    #pragma unroll
    for (int off = 32; off > 0; off >>= 1) {
        acc_n  += __shfl_down(acc_n,  off, 64);
        acc_op += __shfl_down(acc_op, off, 64);
        acc_d  += __shfl_down(acc_d,  off, 64);
        acc_r  += __shfl_down(acc_r,  off, 64);
        acc_g  += __shfl_down(acc_g,  off, 64);
        acc_b  += __shfl_down(acc_b,  off, 64);
    }

    if (lane == 0) {
        out_counts[wid]      = acc_n;     // total_samples stored as float
        out_opacity[wid]     = acc_op;
        out_depth[wid]       = acc_d;
        out_rgb[wid * 3 + 0] = acc_r;
        out_rgb[wid * 3 + 1] = acc_g;
        out_rgb[wid * 3 + 2] = acc_b;
    }
}

extern "C" void kernel_launch(void* const* d_in, const int* in_sizes, int n_in,
                              void* d_out, int out_size, void* d_ws, size_t ws_size,
                              hipStream_t stream) {
    const float* sigmas = (const float*)d_in[0];
    const float* rgbs   = (const float*)d_in[1];
    const float* deltas = (const float*)d_in[2];
    const float* ts     = (const float*)d_in[3];
    const int*   rays_a = (const int*)d_in[4];
    const float* thr    = (const float*)d_in[5];

    const int n_rays = in_sizes[4] / 3;
    float* out = (float*)d_out;

    // 4 waves (rays) per 256-thread block; ray counts cycle (32,64,128,256)
    // so each block is perfectly load-balanced at 480 samples.
    const int blocks = (n_rays + 3) / 4;
    vr_fwd_kernel<<<blocks, 256, 0, stream>>>(sigmas, rgbs, deltas, ts, rays_a,
                                              thr, out, n_rays);
}

// Round 2
// 43.971 us; speedup vs baseline: 1.0220x; 1.0220x over previous
//
#include <hip/hip_runtime.h>

// Volume rendering composite forward — ILP-4 per lane, one wave per ray.
// Lane l owns samples [4l, 4l+4) of each 256-sample chunk: float4 loads for
// sigmas/deltas/ts, 3x float4 for rgbs, float4 store for w. Local 4-prefix +
// one 64-wide shfl scan of lane totals gives the exclusive cumsum; T chained
// as T_{k+1} = T_k * exp(-sd_k) so only 5 exps per lane-chunk.

__global__ __launch_bounds__(256) void vr_fwd_kernel(
    const float* __restrict__ sigmas,
    const float* __restrict__ rgbs,
    const float* __restrict__ deltas,
    const float* __restrict__ ts,
    const int*   __restrict__ rays_a,
    const float* __restrict__ thr_p,
    float* __restrict__ out,   // counts | opacity | depth | rgb | w
    int n_rays)
{
    const int wid  = (int)((blockIdx.x * 256u + threadIdx.x) >> 6);
    const int lane = (int)(threadIdx.x & 63u);
    if (wid >= n_rays) return;

    const int   start = rays_a[wid * 3 + 1];
    const int   count = rays_a[wid * 3 + 2];
    const float thr   = thr_p[0];
    const bool  al4   = ((start & 3) == 0);   // float4 path alignment guard

    float* __restrict__ out_counts  = out;
    float* __restrict__ out_opacity = out + n_rays;
    float* __restrict__ out_depth   = out + 2 * n_rays;
    float* __restrict__ out_rgb     = out + 3 * n_rays;
    float* __restrict__ out_w       = out + 6 * n_rays;

    float carry = 0.0f;
    float acc_n = 0.0f, acc_op = 0.0f, acc_d = 0.0f;
    float acc_r = 0.0f, acc_g = 0.0f, acc_b = 0.0f;

    for (int base = 0; base < count; base += 256) {
        const int li  = base + lane * 4;   // first of my 4 samples (ray-local)
        const int gi  = start + li;        // global sample index
        const int rem = count - li;        // how many of my 4 are in-range

        float sd[4] = {0.f, 0.f, 0.f, 0.f};
        float tv[4] = {0.f, 0.f, 0.f, 0.f};
        float cr[4] = {0.f, 0.f, 0.f, 0.f};
        float cg[4] = {0.f, 0.f, 0.f, 0.f};
        float cb[4] = {0.f, 0.f, 0.f, 0.f};

        if (al4 && rem >= 4) {
            const float4 sg = *reinterpret_cast<const float4*>(sigmas + gi);
            const float4 dl = *reinterpret_cast<const float4*>(deltas + gi);
            const float4 t4 = *reinterpret_cast<const float4*>(ts + gi);
            sd[0] = sg.x * dl.x; sd[1] = sg.y * dl.y;
            sd[2] = sg.z * dl.z; sd[3] = sg.w * dl.w;
            tv[0] = t4.x; tv[1] = t4.y; tv[2] = t4.z; tv[3] = t4.w;
            const float4* rp = reinterpret_cast<const float4*>(rgbs + 3 * gi);
            const float4 A = rp[0], B = rp[1], C = rp[2];
            cr[0] = A.x; cg[0] = A.y; cb[0] = A.z;
            cr[1] = A.w; cg[1] = B.x; cb[1] = B.y;
            cr[2] = B.z; cg[2] = B.w; cb[2] = C.x;
            cr[3] = C.y; cg[3] = C.z; cb[3] = C.w;
        } else if (rem > 0) {
            #pragma unroll
            for (int k = 0; k < 4; ++k) {
                if (k < rem) {
                    sd[k] = sigmas[gi + k] * deltas[gi + k];
                    tv[k] = ts[gi + k];
                    cr[k] = rgbs[3 * (gi + k) + 0];
                    cg[k] = rgbs[3 * (gi + k) + 1];
                    cb[k] = rgbs[3 * (gi + k) + 2];
                }
            }
        }

        // local inclusive prefix over my 4 samples
        const float p1 = sd[0] + sd[1];
        const float p2 = p1 + sd[2];
        const float p3 = p2 + sd[3];

        // 64-wide inclusive scan of lane totals
        float sc = p3;
        #pragma unroll
        for (int off = 1; off < 64; off <<= 1) {
            const float up = __shfl_up(sc, off, 64);
            if (lane >= off) sc += up;
        }
        const float wave_total = __shfl(sc, 63, 64);
        const float lex = carry + (sc - p3);   // exclusive prefix before my 4
        carry += wave_total;

        // T chain: one exp for the lane base, one exp(-sd) per element
        // (reused for a = 1 - exp(-sd)).
        float T = __expf(-lex);
        float wv[4];
        #pragma unroll
        for (int k = 0; k < 4; ++k) {
            const float e     = __expf(-sd[k]);
            const bool  alive = (T >= thr);
            const float w     = alive ? (1.0f - e) * T : 0.0f;
            wv[k] = w;
            if (alive && k < rem) acc_n += 1.0f;   // count only real samples
            acc_op += w;
            acc_d  += w * tv[k];
            acc_r  += w * cr[k];
            acc_g  += w * cg[k];
            acc_b  += w * cb[k];
            T *= e;
        }

        if (al4 && rem >= 4) {
            *reinterpret_cast<float4*>(out_w + gi) =
                make_float4(wv[0], wv[1], wv[2], wv[3]);
        } else if (rem > 0) {
            #pragma unroll
            for (int k = 0; k < 4; ++k)
                if (k < rem) out_w[gi + k] = wv[k];
        }
    }

    // butterfly reduce the 6 accumulators across the wave
    #pragma unroll
    for (int off = 32; off > 0; off >>= 1) {
        acc_n  += __shfl_down(acc_n,  off, 64);
        acc_op += __shfl_down(acc_op, off, 64);
        acc_d  += __shfl_down(acc_d,  off, 64);
        acc_r  += __shfl_down(acc_r,  off, 64);
        acc_g  += __shfl_down(acc_g,  off, 64);
        acc_b  += __shfl_down(acc_b,  off, 64);
    }

    if (lane == 0) {
        out_counts[wid]      = acc_n;     // total_samples stored as float
        out_opacity[wid]     = acc_op;
        out_depth[wid]       = acc_d;
        out_rgb[wid * 3 + 0] = acc_r;
        out_rgb[wid * 3 + 1] = acc_g;
        out_rgb[wid * 3 + 2] = acc_b;
    }
}

extern "C" void kernel_launch(void* const* d_in, const int* in_sizes, int n_in,
                              void* d_out, int out_size, void* d_ws, size_t ws_size,
                              hipStream_t stream) {
    const float* sigmas = (const float*)d_in[0];
    const float* rgbs   = (const float*)d_in[1];
    const float* deltas = (const float*)d_in[2];
    const float* ts     = (const float*)d_in[3];
    const int*   rays_a = (const int*)d_in[4];
    const float* thr    = (const float*)d_in[5];

    const int n_rays = in_sizes[4] / 3;
    float* out = (float*)d_out;

    // 4 waves (rays) per 256-thread block; counts cycle (32,64,128,256) so
    // each block handles one ray of each size (one chunk iteration per wave).
    const int blocks = (n_rays + 3) / 4;
    vr_fwd_kernel<<<blocks, 256, 0, stream>>>(sigmas, rgbs, deltas, ts, rays_a,
                                              thr, out, n_rays);
}

// Round 3
// 40.385 us; speedup vs baseline: 1.1127x; 1.0888x over previous
//
#include <hip/hip_runtime.h>

// Volume rendering composite forward — same-size ray packing.
// Rays are binned by class c = ray_idx % 4 (data has counts cycling
// 32/64/128/256). Class-c rays get a 2^(3+c)-lane subgroup (4 samples/lane),
// 8>>c rays per 64-lane wave. Segmented scan/reduce via __shfl width=sgW.
// Chunk loop + guards keep it correct for ANY counts; the packing is only a
// performance assumption.

__global__ __launch_bounds__(256) void vr_fwd_kernel(
    const float* __restrict__ sigmas,
    const float* __restrict__ rgbs,
    const float* __restrict__ deltas,
    const float* __restrict__ ts,
    const int*   __restrict__ rays_a,
    const float* __restrict__ thr_p,
    float* __restrict__ out,   // counts | opacity | depth | rgb | w
    int n_rays, int b0, int b1, int b2, int b3)
{
    const int wid  = (int)((blockIdx.x * 256u + threadIdx.x) >> 6);
    const int lane = (int)(threadIdx.x & 63u);
    if (wid >= b3) return;

    // class + class-local wave ordinal (wave-uniform branches)
    int cls, wloc;
    if      (wid < b0) { cls = 0; wloc = wid; }
    else if (wid < b1) { cls = 1; wloc = wid - b0; }
    else if (wid < b2) { cls = 2; wloc = wid - b1; }
    else               { cls = 3; wloc = wid - b2; }

    const int sgW    = 8 << cls;          // lanes per subgroup
    const int rpw    = 8 >> cls;          // rays per wave
    const int sgId   = lane >> (3 + cls);
    const int sgLane = lane & (sgW - 1);

    const int ray = (wloc * rpw + sgId) * 4 + cls;  // class c = rays with idx%4==c
    const bool have_ray = (ray < n_rays);

    int start = 0, count = 0;
    if (have_ray) {
        start = rays_a[ray * 3 + 1];
        count = rays_a[ray * 3 + 2];
    }
    const float thr = thr_p[0];
    const bool  al4 = ((start & 3) == 0);

    float* __restrict__ out_counts  = out;
    float* __restrict__ out_opacity = out + n_rays;
    float* __restrict__ out_depth   = out + 2 * n_rays;
    float* __restrict__ out_rgb     = out + 3 * n_rays;
    float* __restrict__ out_w       = out + 6 * n_rays;

    float carry = 0.0f;
    float acc_n = 0.0f, acc_op = 0.0f, acc_d = 0.0f;
    float acc_r = 0.0f, acc_g = 0.0f, acc_b = 0.0f;

    for (int base = 0; base < count; base += sgW * 4) {
        const int li  = base + sgLane * 4;  // ray-local first sample
        const int gi  = start + li;
        const int rem = count - li;         // how many of my 4 are real

        float sd[4] = {0.f, 0.f, 0.f, 0.f};
        float tv[4] = {0.f, 0.f, 0.f, 0.f};
        float cr[4] = {0.f, 0.f, 0.f, 0.f};
        float cg[4] = {0.f, 0.f, 0.f, 0.f};
        float cb[4] = {0.f, 0.f, 0.f, 0.f};

        if (al4 && rem >= 4) {
            const float4 sg = *reinterpret_cast<const float4*>(sigmas + gi);
            const float4 dl = *reinterpret_cast<const float4*>(deltas + gi);
            const float4 t4 = *reinterpret_cast<const float4*>(ts + gi);
            sd[0] = sg.x * dl.x; sd[1] = sg.y * dl.y;
            sd[2] = sg.z * dl.z; sd[3] = sg.w * dl.w;
            tv[0] = t4.x; tv[1] = t4.y; tv[2] = t4.z; tv[3] = t4.w;
            const float4* rp = reinterpret_cast<const float4*>(rgbs + 3 * gi);
            const float4 A = rp[0], B = rp[1], C = rp[2];
            cr[0] = A.x; cg[0] = A.y; cb[0] = A.z;
            cr[1] = A.w; cg[1] = B.x; cb[1] = B.y;
            cr[2] = B.z; cg[2] = B.w; cb[2] = C.x;
            cr[3] = C.y; cg[3] = C.z; cb[3] = C.w;
        } else if (rem > 0) {
            #pragma unroll
            for (int k = 0; k < 4; ++k) {
                if (k < rem) {
                    sd[k] = sigmas[gi + k] * deltas[gi + k];
                    tv[k] = ts[gi + k];
                    cr[k] = rgbs[3 * (gi + k) + 0];
                    cg[k] = rgbs[3 * (gi + k) + 1];
                    cb[k] = rgbs[3 * (gi + k) + 2];
                }
            }
        }

        // local inclusive prefix over my 4 samples
        const float p1 = sd[0] + sd[1];
        const float p2 = p1 + sd[2];
        const float p3 = p2 + sd[3];

        // subgroup-wide inclusive scan of lane totals (log2(sgW) steps)
        float sc = p3;
        for (int off = 1; off < sgW; off <<= 1) {
            const float up = __shfl_up(sc, off, sgW);
            if (sgLane >= off) sc += up;
        }
        const float sg_total = __shfl(sc, sgW - 1, sgW);
        const float lex = carry + (sc - p3);   // exclusive prefix before my 4
        carry += sg_total;

        // T chain: one exp for the lane base, one exp(-sd) per element
        float T = __expf(-lex);
        float wv[4];
        #pragma unroll
        for (int k = 0; k < 4; ++k) {
            const float e     = __expf(-sd[k]);
            const bool  alive = (T >= thr);
            const float w     = alive ? (1.0f - e) * T : 0.0f;
            wv[k] = w;
            if (alive && k < rem) acc_n += 1.0f;
            acc_op += w;
            acc_d  += w * tv[k];
            acc_r  += w * cr[k];
            acc_g  += w * cg[k];
            acc_b  += w * cb[k];
            T *= e;
        }

        if (al4 && rem >= 4) {
            *reinterpret_cast<float4*>(out_w + gi) =
                make_float4(wv[0], wv[1], wv[2], wv[3]);
        } else if (rem > 0) {
            #pragma unroll
            for (int k = 0; k < 4; ++k)
                if (k < rem) out_w[gi + k] = wv[k];
        }
    }

    // subgroup reduce (leader = sgLane 0 gets the true sum)
    for (int off = sgW >> 1; off > 0; off >>= 1) {
        acc_n  += __shfl_down(acc_n,  off, sgW);
        acc_op += __shfl_down(acc_op, off, sgW);
        acc_d  += __shfl_down(acc_d,  off, sgW);
        acc_r  += __shfl_down(acc_r,  off, sgW);
        acc_g  += __shfl_down(acc_g,  off, sgW);
        acc_b  += __shfl_down(acc_b,  off, sgW);
    }

    if (sgLane == 0 && have_ray) {
        out_counts[ray]      = acc_n;     // total_samples stored as float
        out_opacity[ray]     = acc_op;
        out_depth[ray]       = acc_d;
        out_rgb[ray * 3 + 0] = acc_r;
        out_rgb[ray * 3 + 1] = acc_g;
        out_rgb[ray * 3 + 2] = acc_b;
    }
}

extern "C" void kernel_launch(void* const* d_in, const int* in_sizes, int n_in,
                              void* d_out, int out_size, void* d_ws, size_t ws_size,
                              hipStream_t stream) {
    const float* sigmas = (const float*)d_in[0];
    const float* rgbs   = (const float*)d_in[1];
    const float* deltas = (const float*)d_in[2];
    const float* ts     = (const float*)d_in[3];
    const int*   rays_a = (const int*)d_in[4];
    const float* thr    = (const float*)d_in[5];

    const int n_rays = in_sizes[4] / 3;
    float* out = (float*)d_out;

    // waves per class: class c holds rays with idx%4==c, packed 8>>c per wave
    int b[4], cum = 0;
    for (int c = 0; c < 4; ++c) {
        const int Kc  = (n_rays - c + 3) / 4;   // rays in class c
        const int rpw = 8 >> c;
        cum += (Kc + rpw - 1) / rpw;
        b[c] = cum;
    }
    const int total_waves = b[3];
    const int blocks = (total_waves + 3) / 4;   // 4 waves per 256-thread block

    vr_fwd_kernel<<<blocks, 256, 0, stream>>>(sigmas, rgbs, deltas, ts, rays_a,
                                              thr, out, n_rays,
                                              b[0], b[1], b[2], b[3]);
}